// Round 9
// baseline (209.165 us; speedup 1.0000x reference)
//
#include <hip/hip_runtime.h>
#include <stdint.h>

// ListwiseLoss: B=524288 rows, H=32. One THREAD per row; coalesced staging.
//   kl_row = sum_valid e_i*(s_i - g_i) / se,  e = exp(s),
//   g_i = s of the (rank_i)-th valid element in index order
// (max-sub and log(se) cancel between the KL sums; eps dropped — validated
//  rounds 1-8, absmax 0.0).
//
// ROUND-9: O(H) LDS counting-sort rank replaces the 1536-inst O(H^2) SWAR
// (round 8: ~5000 VALU insts/wave, 39% busy, 31% occupancy).
//  - validity fused into staged rank byte: er = mask ? r : 0 (bucket 0 =
//    invalid, so rank-among-valid is automatic; nv = 32 - cnt0).
//  - per-thread 33-byte LDS histogram overlaying the consumed er row;
//    pass A: hist[er]++; SWAR byte prefix in regs; pass B: j = pref[er]++
//    (rank + stable tie-break in one RMW).
//  - staging: ranks as bytes (36 B/row), scores as bf16 (68 B/row incl
//    park slot at +64). LDS 26.7 KB/block -> 6 blocks/CU (75% occ cap).
// Same-wave in-order DS ordering (no __syncthreads in hot path; round-8
// precedent). Odd dword strides (9, 17) -> conflict-free row access.

#define H 32
#define BLK 256
#define WPB 4
#define RSTRIDE 36                  // er/hist row bytes (9 dwords, odd)
#define SSTRIDE 68                  // score row bytes (17 dwords, odd)
#define RREGION (64 * RSTRIDE)      // 2304 B per wave
#define SREGION (64 * SSTRIDE)      // 4352 B per wave

__global__ __launch_bounds__(BLK) void listwise_kernel(
    const float* __restrict__ scores,
    const int* __restrict__ rankings,
    const unsigned char* __restrict__ mask_u8,
    float* __restrict__ part_kl,
    float* __restrict__ part_cnt,
    int nrows)
{
    __shared__ unsigned char rbuf[WPB * RREGION];   // 9216 B
    __shared__ unsigned char sbuf[WPB * SREGION];   // 17408 B
    __shared__ float s_kl[WPB], s_cnt[WPB];

    const int tid  = threadIdx.x;
    const int lane = tid & 63;
    const int wid  = tid >> 6;
    unsigned char* rw  = rbuf + wid * RREGION;
    unsigned char* sw  = sbuf + wid * SREGION;
    unsigned char* myr = rw + lane * RSTRIDE;   // my er row / histogram
    unsigned char* mys = sw + lane * SSTRIDE;   // my bf16 score / gather row
    const int wrow0 = blockIdx.x * BLK + wid * 64;

    // mask dtype detect (bool=1B vs int32=4B); wave-uniform branch
    unsigned char probe = mask_u8[lane];
    const bool mask_is_i32 =
        (__ballot(((lane & 3) != 0) && (probe != 0)) == 0ull);

    float kl = 0.0f, cnt = 0.0f;
    uint32_t er8[8], sp[16];
    bool have = false;

    if (wrow0 + 64 <= nrows) {
        have = true;
        const size_t E0 = (size_t)wrow0 * H;

        // ---- stage er bytes (mask fused): 8 iters x 4 elems/lane, coalesced
        #pragma unroll
        for (int c = 0; c < 8; ++c) {
            const int chunk = lane + 64 * c;            // 4-elem chunk id
            const uint4 r4 = *(const uint4*)(rankings + E0 + 4 * chunk);
            uint32_t m0, m1, m2, m3;
            if (mask_is_i32) {
                const uint4 m4 =
                    *(const uint4*)((const uint32_t*)mask_u8 + E0 + 4 * chunk);
                m0 = m4.x; m1 = m4.y; m2 = m4.z; m3 = m4.w;
            } else {
                const uint32_t md = *(const uint32_t*)(mask_u8 + E0 + 4 * chunk);
                m0 = md & 0xFFu; m1 = md & 0xFF00u;
                m2 = md & 0xFF0000u; m3 = md & 0xFF000000u;
            }
            const uint32_t e0 = m0 ? (r4.x & 0xFFu) : 0u;
            const uint32_t e1 = m1 ? (r4.y & 0xFFu) : 0u;
            const uint32_t e2 = m2 ? (r4.z & 0xFFu) : 0u;
            const uint32_t e3 = m3 ? (r4.w & 0xFFu) : 0u;
            const uint32_t erw = e0 | (e1 << 8) | (e2 << 16) | (e3 << 24);
            *(uint32_t*)(rw + (chunk >> 3) * RSTRIDE + (chunk & 7) * 4) = erw;
        }

        // ---- stage scores as bf16 pairs: 8 iters x 4 elems/lane
        #pragma unroll
        for (int c = 0; c < 8; ++c) {
            const int chunk = lane + 64 * c;
            const uint4 s4 = *(const uint4*)((const uint32_t*)scores + E0 + 4 * chunk);
            const uint32_t d0 = ((s4.x + 0x8000u) >> 16) | ((s4.y + 0x8000u) & 0xFFFF0000u);
            const uint32_t d1 = ((s4.z + 0x8000u) >> 16) | ((s4.w + 0x8000u) & 0xFFFF0000u);
            unsigned char* dst = sw + (chunk >> 3) * SSTRIDE + (chunk & 7) * 8;
            *(uint32_t*)(dst)     = d0;
            *(uint32_t*)(dst + 4) = d1;
        }

        // ---- read my rows into regs
        #pragma unroll
        for (int d = 0; d < 8; ++d) er8[d] = *(const uint32_t*)(myr + 4 * d);
        #pragma unroll
        for (int w = 0; w < 16; ++w) sp[w] = *(const uint32_t*)(mys + 4 * w);
    } else if (wrow0 + lane < nrows) {
        // ---- tail (not hit at B=524288): direct per-thread loads
        have = true;
        const size_t E = (size_t)(wrow0 + lane) * H;
        #pragma unroll
        for (int d = 0; d < 8; ++d) {
            uint32_t er = 0;
            #pragma unroll
            for (int q = 0; q < 4; ++q) {
                const int idx = 4 * d + q;
                const int r = rankings[E + idx];
                const int mk = mask_is_i32 ? ((const int*)mask_u8)[E + idx]
                                           : (int)mask_u8[E + idx];
                er |= (mk != 0 ? ((uint32_t)r & 0xFFu) : 0u) << (8 * q);
            }
            er8[d] = er;
        }
        #pragma unroll
        for (int w = 0; w < 16; ++w) {
            const uint32_t a = __float_as_uint(scores[E + 2 * w]);
            const uint32_t b = __float_as_uint(scores[E + 2 * w + 1]);
            sp[w] = ((a + 0x8000u) >> 16) | ((b + 0x8000u) & 0xFFFF0000u);
        }
    }

    if (have) {
        // ---- compact valid bf16 scores into my gather row (park at +64)
        int jp = 0;
        #pragma unroll
        for (int i = 0; i < H; ++i) {
            const uint32_t b = (er8[i >> 2] >> ((i & 3) * 8)) & 0xFFu;
            const unsigned short val =
                (unsigned short)((i & 1) ? (sp[i >> 1] >> 16) : sp[i >> 1]);
            const bool valid = b != 0u;
            *(unsigned short*)(mys + (valid ? 2 * jp : 64)) = val;
            jp += valid ? 1 : 0;
        }

        // ---- histogram zero (36 B over my consumed er row)
        #pragma unroll
        for (int w = 0; w < 9; ++w) *(uint32_t*)(myr + 4 * w) = 0u;

        // ---- pass A: bucket counts (bucket 0 = invalid)
        #pragma unroll
        for (int i = 0; i < H; ++i) {
            const uint32_t b = (er8[i >> 2] >> ((i & 3) * 8)) & 0xFFu;
            unsigned char* a = myr + b;
            *a = (unsigned char)(*a + 1);
        }

        // ---- SWAR byte-wise exclusive prefix (valid-only: minus cnt0)
        uint32_t pf_cnt0, nv;
        {
            uint32_t run = 0;
            const uint32_t M = 0x01010101u;
            uint32_t h0 = *(const uint32_t*)(myr);
            pf_cnt0 = h0 & 0xFFu;                 // invalid count
            nv = 32u - pf_cnt0;
            const uint32_t sub = pf_cnt0 * M;
            #pragma unroll
            for (int w = 0; w < 9; ++w) {
                const uint32_t x = (w == 0) ? h0 : *(const uint32_t*)(myr + 4 * w);
                uint32_t p = x + (x << 8);
                p += (p << 16);                    // inclusive prefix per byte
                uint32_t q = p - x;                // exclusive within dword
                if (w == 0) q |= pf_cnt0;          // byte0 := cnt0 (no borrow)
                *(uint32_t*)(myr + 4 * w) = q + run * M - sub;
                run += p >> 24;                    // dword total
            }
        }

        // ---- pass B: j = pref[er]++ (rank + stable tie-break), gather, acc
        float se = 0.0f, num = 0.0f;
        #pragma unroll
        for (int i = 0; i < H; ++i) {
            const uint32_t b = (er8[i >> 2] >> ((i & 3) * 8)) & 0xFFu;
            unsigned char* a = myr + b;
            const uint32_t j = *a;
            *a = (unsigned char)(j + 1);
            const bool valid = b != 0u;
            const int go = valid ? (int)(2 * j) : 64;
            const float g = __uint_as_float(
                ((uint32_t)(*(const unsigned short*)(mys + go))) << 16);
            const uint32_t sw_ = sp[i >> 1];
            const float s_i = __uint_as_float((i & 1) ? (sw_ & 0xFFFF0000u)
                                                      : (sw_ << 16));
            float e = __expf(s_i);
            e = valid ? e : 0.0f;
            const float d2 = valid ? (s_i - g) : 0.0f;
            se += e;
            num = __builtin_fmaf(e, d2, num);
        }
        if ((int)nv > 1) { kl = __fdividef(num, se); cnt = 1.0f; }
    }

    // ---- block reduction; unconditional partial write (no memset/atomics)
    #pragma unroll
    for (int m = 32; m >= 1; m >>= 1) {
        kl  += __shfl_xor(kl, m);
        cnt += __shfl_xor(cnt, m);
    }
    if (lane == 0) { s_kl[wid] = kl; s_cnt[wid] = cnt; }
    __syncthreads();
    if (tid == 0) {
        part_kl[blockIdx.x]  = s_kl[0] + s_kl[1] + s_kl[2] + s_kl[3];
        part_cnt[blockIdx.x] = s_cnt[0] + s_cnt[1] + s_cnt[2] + s_cnt[3];
    }
}

__global__ __launch_bounds__(256) void finalize_kernel(
    const float* __restrict__ part_kl,
    const float* __restrict__ part_cnt,
    float* __restrict__ out, int nblk)
{
    float k = 0.0f, c = 0.0f;
    for (int i = threadIdx.x; i < nblk; i += 256) {
        k += part_kl[i];
        c += part_cnt[i];
    }
    #pragma unroll
    for (int m = 32; m >= 1; m >>= 1) {
        k += __shfl_xor(k, m);
        c += __shfl_xor(c, m);
    }
    __shared__ float sk[4], sc[4];
    const int wid = threadIdx.x >> 6;
    if ((threadIdx.x & 63) == 0) { sk[wid] = k; sc[wid] = c; }
    __syncthreads();
    if (threadIdx.x == 0) {
        float K = sk[0] + sk[1] + sk[2] + sk[3];
        float C = sc[0] + sc[1] + sc[2] + sc[3];
        if (C < 1.0f) C = 1.0f;
        out[0] = K / C;
    }
}

extern "C" void kernel_launch(void* const* d_in, const int* in_sizes, int n_in,
                              void* d_out, int out_size, void* d_ws, size_t ws_size,
                              hipStream_t stream) {
    const float* scores = (const float*)d_in[0];
    const int* rankings = (const int*)d_in[1];
    const unsigned char* mask = (const unsigned char*)d_in[2];
    float* out = (float*)d_out;

    const int total = in_sizes[0];       // B*H = 16777216
    const int nrows = total / H;         // 524288 rows
    const int blocks = (nrows + BLK - 1) / BLK;   // 2048

    float* part_kl  = (float*)d_ws;               // [0, blocks)
    float* part_cnt = (float*)d_ws + blocks;      // [blocks, 2*blocks)

    listwise_kernel<<<blocks, BLK, 0, stream>>>(
        scores, rankings, mask, part_kl, part_cnt, nrows);

    finalize_kernel<<<1, 256, 0, stream>>>(part_kl, part_cnt, out, blocks);
}